// Round 1
// baseline (170.137 us; speedup 1.0000x reference)
//
#include <hip/hip_runtime.h>
#include <hip/hip_bf16.h>
#include <hip/hip_fp16.h>
#include <math.h>

// InnerProductDecoder: out[e] = sigmoid(dot(z1[src[e]], z2[dst[e]])), D=128.
//
// R3: test the latency/issue-bound hypothesis on the gather phase.
// R2 counters: ipd_h 43.5us, hbm 3.38 TB/s (42%), VALUBusy 27%, occ 60% --
// no pipe saturated. Changes vs R2:
//   1. v_dot2_f32_f16 (fdot2) -- 4 dot ops/edge-lane instead of 16 cvt + 8 fma
//   2. persistent grid-stride gather (2048 blocks = 32 waves/CU) with
//      next-iteration index prefetch (hides idx-load latency under row loads)
//   3. 32-bit byte offsets (node*256 fits u32) to trim address VALU
// Prediction: if latency-bound, gather -> ~33-37us, hbm -> ~4.0-4.4 TB/s,
// FETCH_SIZE unchanged. If unchanged -> EA-random-BW bound; next round = edge
// sort by src block to cut EA bytes.
// Accuracy unchanged (fp16 storage, fp32 accumulate): absmax was 0.0039 << 2e-2.

#define D_FEAT 128

typedef _Float16 half2v __attribute__((ext_vector_type(2)));

// ---------------- Phase A: fp32 -> fp16 conversion (streaming) --------------
__global__ __launch_bounds__(256) void convert_kernel(
    const float* __restrict__ z1, const float* __restrict__ z2,
    __half* __restrict__ z1h, __half* __restrict__ z2h, int n8) {
  const int i = blockIdx.x * blockDim.x + threadIdx.x;
  if (i >= 2 * n8) return;
  const int which = (i < n8) ? 0 : 1;
  const int j = which ? (i - n8) : i;
  const float* src = which ? z2 : z1;
  __half* dst = which ? z2h : z1h;

  const float4* p = (const float4*)src + 2 * (size_t)j;
  const float4 a = p[0];
  const float4 b = p[1];
  union { __half2 h[4]; float4 f; } u;
  u.h[0] = __floats2half2_rn(a.x, a.y);
  u.h[1] = __floats2half2_rn(a.z, a.w);
  u.h[2] = __floats2half2_rn(b.x, b.y);
  u.h[3] = __floats2half2_rn(b.z, b.w);
  ((float4*)dst)[j] = u.f;
}

// ---------------- Phase B: fp16 gather + fdot2 + sigmoid --------------------
#define LANES_H 16  // 16 lanes x 16 B = 256 B = one fp16 row
#define EPG 4       // edges per 16-lane group

__device__ __forceinline__ float dot8_h(float4 a, float4 b) {
  const half2v* ha = (const half2v*)&a;
  const half2v* hb = (const half2v*)&b;
  float acc = 0.f;
#pragma unroll
  for (int k = 0; k < 4; ++k) {
#if defined(__has_builtin) && __has_builtin(__builtin_amdgcn_fdot2)
    acc = __builtin_amdgcn_fdot2(ha[k], hb[k], acc, false);
#else
    const float2 fa = __half22float2(((const __half2*)&a)[k]);
    const float2 fb = __half22float2(((const __half2*)&b)[k]);
    acc += fa.x * fb.x + fa.y * fb.y;
#endif
  }
  return acc;
}

__device__ __forceinline__ float sigmoidf_(float x) {
  return 1.0f / (1.0f + __expf(-x));
}

__global__ __launch_bounds__(256) void ipd_h_kernel(
    const __half* __restrict__ z1h, const __half* __restrict__ z2h,
    const int* __restrict__ edge_index, float* __restrict__ out,
    int n_edges, int ngroups) {
  const int lane = threadIdx.x & (LANES_H - 1);
  const int lane_b = lane << 4;  // byte offset within a 256 B row
  int g = (blockIdx.x * blockDim.x + threadIdx.x) >> 4;
  const int gstride = (gridDim.x * blockDim.x) >> 4;
  if (g >= ngroups) return;

  const int* __restrict__ srcp = edge_index;
  const int* __restrict__ dstp = edge_index + n_edges;
  const char* __restrict__ z1b = (const char*)z1h;
  const char* __restrict__ z2b = (const char*)z2h;

  // Prologue: indices for the first group.
  int4 s4, d4;
  {
    const int rem = n_edges - g * EPG;
    if (rem >= EPG) {
      s4 = *(const int4*)(srcp + g * EPG);
      d4 = *(const int4*)(dstp + g * EPG);
    } else {  // generic tail guard (never taken for E=600k)
      const int b = g * EPG;
      s4.x = srcp[b]; d4.x = dstp[b];
      s4.y = rem > 1 ? srcp[b + 1] : 0; d4.y = rem > 1 ? dstp[b + 1] : 0;
      s4.z = rem > 2 ? srcp[b + 2] : 0; d4.z = rem > 2 ? dstp[b + 2] : 0;
      s4.w = 0; d4.w = 0;
    }
  }

  while (true) {
    const int gn = g + gstride;
    const bool more = gn < ngroups;

    // Prefetch next group's indices -- issues before this group's compute,
    // so the idx-load latency hides under the row-load wait.
    int4 s4n, d4n;
    if (more) {
      const int remn = n_edges - gn * EPG;
      if (remn >= EPG) {
        s4n = *(const int4*)(srcp + gn * EPG);
        d4n = *(const int4*)(dstp + gn * EPG);
      } else {
        const int b = gn * EPG;
        s4n.x = srcp[b]; d4n.x = dstp[b];
        s4n.y = remn > 1 ? srcp[b + 1] : 0; d4n.y = remn > 1 ? dstp[b + 1] : 0;
        s4n.z = remn > 2 ? srcp[b + 2] : 0; d4n.z = remn > 2 ? dstp[b + 2] : 0;
        s4n.w = 0; d4n.w = 0;
      }
    }

    // 8 independent 16 B row loads in flight. 32-bit byte offsets.
    const unsigned so[EPG] = {(unsigned)s4.x << 8, (unsigned)s4.y << 8,
                              (unsigned)s4.z << 8, (unsigned)s4.w << 8};
    const unsigned dofs[EPG] = {(unsigned)d4.x << 8, (unsigned)d4.y << 8,
                                (unsigned)d4.z << 8, (unsigned)d4.w << 8};
    float4 va[EPG], vb[EPG];
#pragma unroll
    for (int i = 0; i < EPG; ++i) {
      va[i] = *(const float4*)(z1b + so[i] + lane_b);
      vb[i] = *(const float4*)(z2b + dofs[i] + lane_b);
    }

    float sum[EPG];
#pragma unroll
    for (int i = 0; i < EPG; ++i) sum[i] = dot8_h(va[i], vb[i]);

#pragma unroll
    for (int off = LANES_H / 2; off > 0; off >>= 1) {
#pragma unroll
      for (int i = 0; i < EPG; ++i) sum[i] += __shfl_xor(sum[i], off, LANES_H);
    }

    if (lane == 0) {
      const int ebase = g * EPG;
      const int rem = n_edges - ebase;
      if (rem >= EPG) {
        float4 o;
        o.x = sigmoidf_(sum[0]);
        o.y = sigmoidf_(sum[1]);
        o.z = sigmoidf_(sum[2]);
        o.w = sigmoidf_(sum[3]);
        *(float4*)(out + ebase) = o;
      } else {
        out[ebase] = sigmoidf_(sum[0]);
        if (rem > 1) out[ebase + 1] = sigmoidf_(sum[1]);
        if (rem > 2) out[ebase + 2] = sigmoidf_(sum[2]);
      }
    }

    if (!more) break;
    g = gn;
    s4 = s4n;
    d4 = d4n;
  }
}

// ---------------- Fallback: fp32 gather (R1 path, ws too small) -------------
#define LANES_F 32

__global__ __launch_bounds__(256) void ipd_f_kernel(
    const float* __restrict__ z1, const float* __restrict__ z2,
    const int* __restrict__ edge_index, float* __restrict__ out, int n_edges) {
  const int tid = blockIdx.x * blockDim.x + threadIdx.x;
  const int lane = tid & (LANES_F - 1);
  const int group = tid / LANES_F;
  const int ebase = group * EPG;
  if (ebase >= n_edges) return;

  const int4 s4 = *(const int4*)(edge_index + ebase);
  const int4 d4 = *(const int4*)(edge_index + n_edges + ebase);
  const int s[EPG] = {s4.x, s4.y, s4.z, s4.w};
  const int d[EPG] = {d4.x, d4.y, d4.z, d4.w};

  float4 va[EPG], vb[EPG];
#pragma unroll
  for (int i = 0; i < EPG; ++i) {
    va[i] = ((const float4*)(z1 + (size_t)s[i] * D_FEAT))[lane];
    vb[i] = ((const float4*)(z2 + (size_t)d[i] * D_FEAT))[lane];
  }

  float sum[EPG];
#pragma unroll
  for (int i = 0; i < EPG; ++i)
    sum[i] = va[i].x * vb[i].x + va[i].y * vb[i].y +
             va[i].z * vb[i].z + va[i].w * vb[i].w;

#pragma unroll
  for (int off = LANES_F / 2; off > 0; off >>= 1) {
#pragma unroll
    for (int i = 0; i < EPG; ++i) sum[i] += __shfl_xor(sum[i], off, LANES_F);
  }

  if (lane == 0) {
    float4 o;
    o.x = sigmoidf_(sum[0]);
    o.y = sigmoidf_(sum[1]);
    o.z = sigmoidf_(sum[2]);
    o.w = sigmoidf_(sum[3]);
    *(float4*)(out + ebase) = o;
  }
}

extern "C" void kernel_launch(void* const* d_in, const int* in_sizes, int n_in,
                              void* d_out, int out_size, void* d_ws, size_t ws_size,
                              hipStream_t stream) {
  const float* z1 = (const float*)d_in[0];
  const float* z2 = (const float*)d_in[1];
  const int* edge_index = (const int*)d_in[2];
  float* out = (float*)d_out;

  const int n_edges = in_sizes[2] / 2;   // edge_index is [2, E]
  const int n_feat_elems = in_sizes[0];  // N_NODES * D_FEAT

  const size_t half_bytes = (size_t)n_feat_elems * sizeof(__half);
  const int block = 256;

  if (ws_size >= 2 * half_bytes && (n_feat_elems % 8) == 0) {
    __half* z1h = (__half*)d_ws;
    __half* z2h = (__half*)((char*)d_ws + half_bytes);

    // Phase A: convert both tensors.
    const int n8 = n_feat_elems / 8;
    const int cgrid = (2 * n8 + block - 1) / block;
    convert_kernel<<<cgrid, block, 0, stream>>>(z1, z2, z1h, z2h, n8);

    // Phase B: persistent fp16 gather. 2048 blocks = 8 blocks/CU * 256 CU
    // (exactly 32 waves/CU at 256 threads/block).
    const int ngroups = (n_edges + EPG - 1) / EPG;
    const long long want = ((long long)ngroups * LANES_H + block - 1) / block;
    const int grid = (int)(want < 2048 ? want : 2048);
    ipd_h_kernel<<<grid, block, 0, stream>>>(z1h, z2h, edge_index, out,
                                             n_edges, ngroups);
  } else {
    const int groups = (n_edges + EPG - 1) / EPG;
    const long long total = (long long)groups * LANES_F;
    const int grid = (int)((total + block - 1) / block);
    ipd_f_kernel<<<grid, block, 0, stream>>>(z1, z2, edge_index, out, n_edges);
  }
}

// Round 2
// 166.526 us; speedup vs baseline: 1.0217x; 1.0217x over previous
//
#include <hip/hip_runtime.h>
#include <hip/hip_bf16.h>
#include <hip/hip_fp16.h>
#include <math.h>

// InnerProductDecoder: out[e] = sigmoid(dot(z1[src[e]], z2[dst[e]])), D=128.
//
// R4 (final settle): R3 refuted the latency/issue-bound hypothesis --
// fdot2 cut VALUBusy 27->18% with ZERO time change; persistent grid cost
// ~1.2us (occupancy 60->53%). The gather is past-L2 random-service bound:
// 141 MB EA @ ~3.3 TB/s across R1/R2/R3 regardless of compute profile.
// Ceiling arithmetic (journal):
//   gather floor = 141 MB @ 3.3 TB/s = 43 us (byte cuts priced out:
//     fp8/int8 fail absmax by 4-12x; sort saves ~13us but costs ~12-15us
//     of serialized dispatches; L2-blocking explodes re-fetch),
//   convert floor = 154 MB streaming = ~26 us,
//   remainder of the 168us wall = harness reset dispatches.
// R4 = R2's flat launch (best measured: 43.4-43.6us) + R3's fdot2 and
// 32-bit byte-offset addressing. Prediction: ipd_h ~43.5us, occ ~60%,
// FETCH 141 MB, total ~168.

#define D_FEAT 128

typedef _Float16 half2v __attribute__((ext_vector_type(2)));

// ---------------- Phase A: fp32 -> fp16 conversion (streaming) --------------
// One thread per 8 floats; 2*float4 in, 1*float4 (8 halves) out. n8 is a
// multiple of 256 here (1.6M), so the which-branch never splits a wave.
__global__ __launch_bounds__(256) void convert_kernel(
    const float* __restrict__ z1, const float* __restrict__ z2,
    __half* __restrict__ z1h, __half* __restrict__ z2h, int n8) {
  const int i = blockIdx.x * blockDim.x + threadIdx.x;
  if (i >= 2 * n8) return;
  const int which = (i < n8) ? 0 : 1;
  const int j = which ? (i - n8) : i;
  const float* src = which ? z2 : z1;
  __half* dst = which ? z2h : z1h;

  const float4* p = (const float4*)src + 2 * (size_t)j;
  const float4 a = p[0];
  const float4 b = p[1];
  union { __half2 h[4]; float4 f; } u;
  u.h[0] = __floats2half2_rn(a.x, a.y);
  u.h[1] = __floats2half2_rn(a.z, a.w);
  u.h[2] = __floats2half2_rn(b.x, b.y);
  u.h[3] = __floats2half2_rn(b.z, b.w);
  ((float4*)dst)[j] = u.f;
}

// ---------------- Phase B: fp16 gather + fdot2 + sigmoid --------------------
#define LANES_H 16  // 16 lanes x 16 B = 256 B = one fp16 row
#define EPG 4       // edges per 16-lane group

__device__ __forceinline__ float dot8_h(float4 a, float4 b) {
  const half2v* ha = (const half2v*)&a;
  const half2v* hb = (const half2v*)&b;
  float acc = 0.f;
#pragma unroll
  for (int k = 0; k < 4; ++k) {
#if defined(__has_builtin) && __has_builtin(__builtin_amdgcn_fdot2)
    acc = __builtin_amdgcn_fdot2(ha[k], hb[k], acc, false);
#else
    const float2 fa = __half22float2(((const __half2*)&a)[k]);
    const float2 fb = __half22float2(((const __half2*)&b)[k]);
    acc += fa.x * fb.x + fa.y * fb.y;
#endif
  }
  return acc;
}

__device__ __forceinline__ float sigmoidf_(float x) {
  return 1.0f / (1.0f + __expf(-x));
}

__global__ __launch_bounds__(256) void ipd_h_kernel(
    const __half* __restrict__ z1h, const __half* __restrict__ z2h,
    const int* __restrict__ edge_index, float* __restrict__ out, int n_edges) {
  const int tid = blockIdx.x * blockDim.x + threadIdx.x;
  const int lane = tid & (LANES_H - 1);
  const int lane_b = lane << 4;  // byte offset within a 256 B row
  const int group = tid / LANES_H;
  const int ebase = group * EPG;
  if (ebase >= n_edges) return;

  const int4 s4 = *(const int4*)(edge_index + ebase);
  const int4 d4 = *(const int4*)(edge_index + n_edges + ebase);

  const char* __restrict__ z1b = (const char*)z1h;
  const char* __restrict__ z2b = (const char*)z2h;

  // 32-bit byte offsets (node*256 <= 25.6M fits u32): trims address VALU.
  const unsigned so[EPG] = {(unsigned)s4.x << 8, (unsigned)s4.y << 8,
                            (unsigned)s4.z << 8, (unsigned)s4.w << 8};
  const unsigned dofs[EPG] = {(unsigned)d4.x << 8, (unsigned)d4.y << 8,
                              (unsigned)d4.z << 8, (unsigned)d4.w << 8};

  // 8 independent 16 B row loads in flight per lane.
  float4 va[EPG], vb[EPG];
#pragma unroll
  for (int i = 0; i < EPG; ++i) {
    va[i] = *(const float4*)(z1b + so[i] + lane_b);
    vb[i] = *(const float4*)(z2b + dofs[i] + lane_b);
  }

  float sum[EPG];
#pragma unroll
  for (int i = 0; i < EPG; ++i) sum[i] = dot8_h(va[i], vb[i]);

#pragma unroll
  for (int off = LANES_H / 2; off > 0; off >>= 1) {
#pragma unroll
    for (int i = 0; i < EPG; ++i) sum[i] += __shfl_xor(sum[i], off, LANES_H);
  }

  if (lane == 0) {
    const int rem = n_edges - ebase;
    if (rem >= EPG) {
      float4 o;
      o.x = sigmoidf_(sum[0]);
      o.y = sigmoidf_(sum[1]);
      o.z = sigmoidf_(sum[2]);
      o.w = sigmoidf_(sum[3]);
      *(float4*)(out + ebase) = o;
    } else {
      out[ebase] = sigmoidf_(sum[0]);
      if (rem > 1) out[ebase + 1] = sigmoidf_(sum[1]);
      if (rem > 2) out[ebase + 2] = sigmoidf_(sum[2]);
    }
  }
}

// ---------------- Fallback: fp32 gather (ws too small) ----------------------
#define LANES_F 32

__global__ __launch_bounds__(256) void ipd_f_kernel(
    const float* __restrict__ z1, const float* __restrict__ z2,
    const int* __restrict__ edge_index, float* __restrict__ out, int n_edges) {
  const int tid = blockIdx.x * blockDim.x + threadIdx.x;
  const int lane = tid & (LANES_F - 1);
  const int group = tid / LANES_F;
  const int ebase = group * EPG;
  if (ebase >= n_edges) return;

  const int4 s4 = *(const int4*)(edge_index + ebase);
  const int4 d4 = *(const int4*)(edge_index + n_edges + ebase);
  const int s[EPG] = {s4.x, s4.y, s4.z, s4.w};
  const int d[EPG] = {d4.x, d4.y, d4.z, d4.w};

  float4 va[EPG], vb[EPG];
#pragma unroll
  for (int i = 0; i < EPG; ++i) {
    va[i] = ((const float4*)(z1 + (size_t)s[i] * D_FEAT))[lane];
    vb[i] = ((const float4*)(z2 + (size_t)d[i] * D_FEAT))[lane];
  }

  float sum[EPG];
#pragma unroll
  for (int i = 0; i < EPG; ++i)
    sum[i] = va[i].x * vb[i].x + va[i].y * vb[i].y +
             va[i].z * vb[i].z + va[i].w * vb[i].w;

#pragma unroll
  for (int off = LANES_F / 2; off > 0; off >>= 1) {
#pragma unroll
    for (int i = 0; i < EPG; ++i) sum[i] += __shfl_xor(sum[i], off, LANES_F);
  }

  if (lane == 0) {
    float4 o;
    o.x = sigmoidf_(sum[0]);
    o.y = sigmoidf_(sum[1]);
    o.z = sigmoidf_(sum[2]);
    o.w = sigmoidf_(sum[3]);
    *(float4*)(out + ebase) = o;
  }
}

extern "C" void kernel_launch(void* const* d_in, const int* in_sizes, int n_in,
                              void* d_out, int out_size, void* d_ws, size_t ws_size,
                              hipStream_t stream) {
  const float* z1 = (const float*)d_in[0];
  const float* z2 = (const float*)d_in[1];
  const int* edge_index = (const int*)d_in[2];
  float* out = (float*)d_out;

  const int n_edges = in_sizes[2] / 2;   // edge_index is [2, E]
  const int n_feat_elems = in_sizes[0];  // N_NODES * D_FEAT

  const size_t half_bytes = (size_t)n_feat_elems * sizeof(__half);
  const int block = 256;

  if (ws_size >= 2 * half_bytes && (n_feat_elems % 8) == 0) {
    __half* z1h = (__half*)d_ws;
    __half* z2h = (__half*)((char*)d_ws + half_bytes);

    // Phase A: convert both tensors (154 MB streaming, ~26 us floor).
    const int n8 = n_feat_elems / 8;
    const int cgrid = (2 * n8 + block - 1) / block;
    convert_kernel<<<cgrid, block, 0, stream>>>(z1, z2, z1h, z2h, n8);

    // Phase B: flat fp16 gather (exact grid -- R2's best-measured config).
    const int groups = (n_edges + EPG - 1) / EPG;
    const long long total = (long long)groups * LANES_H;
    const int grid = (int)((total + block - 1) / block);
    ipd_h_kernel<<<grid, block, 0, stream>>>(z1h, z2h, edge_index, out, n_edges);
  } else {
    const int groups = (n_edges + EPG - 1) / EPG;
    const long long total = (long long)groups * LANES_F;
    const int grid = (int)((total + block - 1) / block);
    ipd_f_kernel<<<grid, block, 0, stream>>>(z1, z2, edge_index, out, n_edges);
  }
}